// Round 10
// baseline (63.916 us; speedup 1.0000x reference)
//
#include <hip/hip_runtime.h>
#include <hip/hip_bf16.h>
#include <hip/hip_cooperative_groups.h>

namespace cg = cooperative_groups;

#define DD 256
#define SS 128
#define BB 16

typedef __attribute__((ext_vector_type(8))) short bf16x8;
typedef __attribute__((ext_vector_type(4))) short bf16x4;
typedef __attribute__((ext_vector_type(4))) float f32x4;

static __device__ __forceinline__ short f2bf(float f) {
    __hip_bfloat16 h = __float2bfloat16(f);
    return *reinterpret_cast<short*>(&h);
}

// swizzled byte offset within a [rows][256 bf16 = 512B] LDS tile
static __device__ __forceinline__ int swz(int r, int kb) {
    return r * 512 + (kb ^ ((r & 7) << 4));
}

// ws layout (floats): sumLg [B][D], sumRg [B][D], absS [B][D]

// ---------------- single cooperative kernel: everything ----------------
// grid 256 = B(16) x 16 d-chunks; 512 threads = 8 waves; 1 block/CU (co-resident).
__global__ __launch_bounds__(512, 2) void k_all(
    const int* __restrict__ X, const float* __restrict__ emb,
    const float* __restrict__ Wl, const float* __restrict__ bl,
    const float* __restrict__ Wr, const float* __restrict__ br,
    const float* __restrict__ Wrel, const float* __restrict__ brel,
    float* __restrict__ sumLg, float* __restrict__ sumRg,
    float* __restrict__ absS, float* __restrict__ out)
{
    __shared__ __align__(16) short Ebf[128 * 256];    // 64 KB, swizzled bf16
    __shared__ __align__(16) float Lcol[16 * 132];    // [d][s]
    __shared__ __align__(16) float Rcol[16 * 132];
    __shared__ float redA[512];                        // reused as pooled[] in phase 2
    __shared__ float redwL[8 * 16];
    __shared__ float redwR[8 * 16];
    __shared__ int toksh[SS];

    const int tid  = threadIdx.x;
    // XCD-bijective swizzle: 32 consecutive logical blocks (2 batches) per XCD
    const int bx   = (blockIdx.x & 7) * 32 + (blockIdx.x >> 3);
    const int b    = bx >> 4;
    const int dc   = bx & 15;
    const int dr0  = dc * 16;
    const int w    = tid >> 6;          // wave 0..7
    const int lane = tid & 63;
    const int lr   = lane & 15, lk = lane >> 4;
    const int c4   = tid & 63;

    if (tid < SS) toksh[tid] = X[b * SS + tid];
    __syncthreads();

    char* Eb = (char*)Ebf;

    // ---- gather batch A (rows i*8+w), issue all 8 loads ----
    float4 ga[8];
#pragma unroll
    for (int i = 0; i < 8; ++i)
        ga[i] = *(const float4*)&emb[(size_t)toksh[i * 8 + w] * DD + c4 * 4];

    // ---- W fragments: f32 -> bf16 in registers (cvt hides under gather) ----
    bf16x8 wlf[8], wrf[8];
    {
        const float* plw = Wl + (size_t)(dr0 + lr) * DD + lk * 8;
        const float* prw = Wr + (size_t)(dr0 + lr) * DD + lk * 8;
#pragma unroll
        for (int ks = 0; ks < 8; ++ks) {
            float4 f0 = *(const float4*)(plw + ks * 32);
            float4 f1 = *(const float4*)(plw + ks * 32 + 4);
            bf16x8 p;
            p[0]=f2bf(f0.x); p[1]=f2bf(f0.y); p[2]=f2bf(f0.z); p[3]=f2bf(f0.w);
            p[4]=f2bf(f1.x); p[5]=f2bf(f1.y); p[6]=f2bf(f1.z); p[7]=f2bf(f1.w);
            wlf[ks] = p;
            f0 = *(const float4*)(prw + ks * 32);
            f1 = *(const float4*)(prw + ks * 32 + 4);
            p[0]=f2bf(f0.x); p[1]=f2bf(f0.y); p[2]=f2bf(f0.z); p[3]=f2bf(f0.w);
            p[4]=f2bf(f1.x); p[5]=f2bf(f1.y); p[6]=f2bf(f1.z); p[7]=f2bf(f1.w);
            wrf[ks] = p;
        }
    }

    // write batch A, then batch B
#pragma unroll
    for (int i = 0; i < 8; ++i) {
        bf16x4 p; p[0]=f2bf(ga[i].x); p[1]=f2bf(ga[i].y); p[2]=f2bf(ga[i].z); p[3]=f2bf(ga[i].w);
        *(bf16x4*)(Eb + swz(i * 8 + w, c4 * 8)) = p;
    }
#pragma unroll
    for (int i = 0; i < 8; ++i)
        ga[i] = *(const float4*)&emb[(size_t)toksh[64 + i * 8 + w] * DD + c4 * 4];
#pragma unroll
    for (int i = 0; i < 8; ++i) {
        bf16x4 p; p[0]=f2bf(ga[i].x); p[1]=f2bf(ga[i].y); p[2]=f2bf(ga[i].z); p[3]=f2bf(ga[i].w);
        *(bf16x4*)(Eb + swz(64 + i * 8 + w, c4 * 8)) = p;
    }
    __syncthreads();

    // ---- MFMA: wave w -> tokens w*16..w*16+15, 16 d's ----
    f32x4 accL = {0.f,0.f,0.f,0.f}, accR = accL;
#pragma unroll
    for (int ks = 0; ks < 8; ++ks) {
        bf16x8 a = *(bf16x8*)(Eb + swz(w * 16 + lr, ks * 64 + lk * 16));
        accL = __builtin_amdgcn_mfma_f32_16x16x32_bf16(a, wlf[ks], accL, 0, 0, 0);
        accR = __builtin_amdgcn_mfma_f32_16x16x32_bf16(a, wrf[ks], accR, 0, 0, 0);
    }
    const float blv = bl[dr0 + lr];
    const float brv = br[dr0 + lr];
    // C mapping (m89-verified): col = lane&15 (d), row = (lane>>4)*4 + reg (token)
#pragma unroll
    for (int reg = 0; reg < 4; ++reg) {
        int s = w * 16 + lk * 4 + reg;
        Lcol[lr * 132 + s] = accL[reg] + blv;
        Rcol[lr * 132 + s] = accR[reg] + brv;
    }
    float tl = (accL[0] + accL[1]) + (accL[2] + accL[3]) + blv * 4.0f;
    float tr = (accR[0] + accR[1]) + (accR[2] + accR[3]) + brv * 4.0f;
    tl += __shfl_xor(tl, 16);  tr += __shfl_xor(tr, 16);
    tl += __shfl_xor(tl, 32);  tr += __shfl_xor(tr, 32);
    if (lane < 16) { redwL[w * 16 + lr] = tl; redwR[w * 16 + lr] = tr; }
    __syncthreads();

    // ---- all-pairs |L_i + R_j|: thread (d, jg) does 4 j's x 128 i's ----
    const int d = tid & 15, jg = tid >> 4;
    float rr[4];
    *(float4*)rr = *(float4*)&Rcol[d * 132 + jg * 4];

    float a0 = 0.f, a1 = 0.f, a2 = 0.f, a3 = 0.f;
    for (int i = 0; i < 128; i += 4) {
        float4 l4 = *(float4*)&Lcol[d * 132 + i];
#pragma unroll
        for (int q = 0; q < 4; ++q) {
            a0 += fabsf(l4.x + rr[q]);
            a1 += fabsf(l4.y + rr[q]);
            a2 += fabsf(l4.z + rr[q]);
            a3 += fabsf(l4.w + rr[q]);
        }
    }
    redA[tid] = (a0 + a1) + (a2 + a3);
    __syncthreads();

    if (tid < 16) {
        float sa = 0.f;
#pragma unroll
        for (int g = 0; g < 32; ++g) sa += redA[g * 16 + tid];
        float sl = 0.f, sr = 0.f;
#pragma unroll
        for (int wv = 0; wv < 8; ++wv) {
            sl += redwL[wv * 16 + tid];
            sr += redwR[wv * 16 + tid];
        }
        absS [b * DD + dr0 + tid] = sa;
        sumLg[b * DD + dr0 + tid] = sl;
        sumRg[b * DD + dr0 + tid] = sr;
    }

    // ---- grid-wide sync, then blocks 0..15 do the final affine ----
    cg::this_grid().sync();

    if (blockIdx.x < BB) {
        const int fb = blockIdx.x;
        float* pooled = redA;   // reuse
        if (tid < DD) {
            float sl = sumLg[fb * DD + tid];
            float sr = sumRg[fb * DD + tid];
            float sa = absS [fb * DD + tid];
            pooled[tid] = (128.0f * (sl + sr) + sa) * (1.0f / 32768.0f);
        }
        __syncthreads();
        if (tid < DD) {
            float acc = brel[tid];
            const float4* w4 = (const float4*)(Wrel + (size_t)tid * DD);
#pragma unroll
            for (int k4 = 0; k4 < DD / 4; ++k4) {
                float4 p = *(float4*)&pooled[k4 * 4];
                float4 wv = w4[k4];
                acc = fmaf(p.x, wv.x, acc);
                acc = fmaf(p.y, wv.y, acc);
                acc = fmaf(p.z, wv.z, acc);
                acc = fmaf(p.w, wv.w, acc);
            }
            out[fb * DD + tid] = acc;
        }
    }
}

extern "C" void kernel_launch(void* const* d_in, const int* in_sizes, int n_in,
                              void* d_out, int out_size, void* d_ws, size_t ws_size,
                              hipStream_t stream) {
    const int*   X    = (const int*)d_in[0];
    const float* emb  = (const float*)d_in[1];
    const float* Wl   = (const float*)d_in[2];
    const float* bl   = (const float*)d_in[3];
    const float* Wr   = (const float*)d_in[4];
    const float* br   = (const float*)d_in[5];
    const float* Wrel = (const float*)d_in[6];
    const float* brel = (const float*)d_in[7];
    float* out = (float*)d_out;

    float* ws    = (float*)d_ws;
    float* sumLg = ws;                 // [B][D]
    float* sumRg = sumLg + BB * DD;    // [B][D]
    float* absS  = sumRg + BB * DD;    // [B][D]

    void* args[] = { (void*)&X, (void*)&emb, (void*)&Wl, (void*)&bl,
                     (void*)&Wr, (void*)&br, (void*)&Wrel, (void*)&brel,
                     (void*)&sumLg, (void*)&sumRg, (void*)&absS, (void*)&out };
    hipLaunchCooperativeKernel((void*)k_all, dim3(BB * 16), dim3(512),
                               args, 0, stream);
}

// Round 11
// 27.889 us; speedup vs baseline: 2.2918x; 2.2918x over previous
//
#include <hip/hip_runtime.h>
#include <hip/hip_bf16.h>

#define DD 256
#define SS 128
#define BB 16

typedef __attribute__((ext_vector_type(8))) short bf16x8;
typedef __attribute__((ext_vector_type(4))) short bf16x4;
typedef __attribute__((ext_vector_type(4))) float f32x4;

static __device__ __forceinline__ short f2bf(float f) {
    __hip_bfloat16 h = __float2bfloat16(f);
    return *reinterpret_cast<short*>(&h);
}

// swizzled byte offset within a [rows][256 bf16 = 512B] LDS tile
static __device__ __forceinline__ int swz(int r, int kb) {
    return r * 512 + (kb ^ ((r & 7) << 4));
}

// ws layout (floats): sumLg [B][D], sumRg [B][D], absS [B][D]

// ---------------- fused: gather + projection (MFMA) + all-pairs ----------------
// grid 256 = B(16) x 16 d-chunks; 512 threads = 8 waves; 1 block/CU.
__global__ __launch_bounds__(512, 2) void k_fused(
    const int* __restrict__ X, const float* __restrict__ emb,
    const float* __restrict__ Wl, const float* __restrict__ bl,
    const float* __restrict__ Wr, const float* __restrict__ br,
    float* __restrict__ sumLg, float* __restrict__ sumRg,
    float* __restrict__ absS)
{
    __shared__ __align__(16) short Ebf[128 * 256];    // 64 KB, swizzled bf16
    __shared__ __align__(16) float Lcol[16 * 132];    // [d][s]
    __shared__ __align__(16) float Rcol[16 * 132];
    __shared__ float redA[512];
    __shared__ float redwL[8 * 16];
    __shared__ float redwR[8 * 16];

    const int tid  = threadIdx.x;
    // XCD-bijective swizzle: 32 consecutive logical blocks (2 batches) per XCD
    const int bx   = (blockIdx.x & 7) * 32 + (blockIdx.x >> 3);
    const int b    = bx >> 4;
    const int dc   = bx & 15;
    const int dr0  = dc * 16;
    const int w    = __builtin_amdgcn_readfirstlane(tid >> 6);  // wave id (SGPR)
    const int lane = tid & 63;
    const int lr   = lane & 15, lk = lane >> 4;

    // ---- 16 wave-uniform token ids -> scalar regs (no LDS, no barrier) ----
    int tok[16];
#pragma unroll
    for (int i = 0; i < 8; ++i) tok[i]     = X[b * SS + i * 8 + w];
#pragma unroll
    for (int i = 0; i < 8; ++i) tok[8 + i] = X[b * SS + 64 + i * 8 + w];

    // ---- issue ALL 16 emb row loads up front (single HBM round trip) ----
    float4 ga[16];
#pragma unroll
    for (int i = 0; i < 16; ++i)
        ga[i] = *(const float4*)&emb[(size_t)tok[i] * DD + lane * 4];

    // ---- W fragments: f32 -> bf16 in registers (runs under gather latency) ----
    bf16x8 wlf[8], wrf[8];
    {
        const float* plw = Wl + (size_t)(dr0 + lr) * DD + lk * 8;
        const float* prw = Wr + (size_t)(dr0 + lr) * DD + lk * 8;
#pragma unroll
        for (int ks = 0; ks < 8; ++ks) {
            float4 f0 = *(const float4*)(plw + ks * 32);
            float4 f1 = *(const float4*)(plw + ks * 32 + 4);
            bf16x8 p;
            p[0]=f2bf(f0.x); p[1]=f2bf(f0.y); p[2]=f2bf(f0.z); p[3]=f2bf(f0.w);
            p[4]=f2bf(f1.x); p[5]=f2bf(f1.y); p[6]=f2bf(f1.z); p[7]=f2bf(f1.w);
            wlf[ks] = p;
            f0 = *(const float4*)(prw + ks * 32);
            f1 = *(const float4*)(prw + ks * 32 + 4);
            p[0]=f2bf(f0.x); p[1]=f2bf(f0.y); p[2]=f2bf(f0.z); p[3]=f2bf(f0.w);
            p[4]=f2bf(f1.x); p[5]=f2bf(f1.y); p[6]=f2bf(f1.z); p[7]=f2bf(f1.w);
            wrf[ks] = p;
        }
    }

    // ---- convert + write E rows (drains ga incrementally) ----
    char* Eb = (char*)Ebf;
#pragma unroll
    for (int i = 0; i < 8; ++i) {
        bf16x4 p; p[0]=f2bf(ga[i].x); p[1]=f2bf(ga[i].y); p[2]=f2bf(ga[i].z); p[3]=f2bf(ga[i].w);
        *(bf16x4*)(Eb + swz(i * 8 + w, lane * 8)) = p;
    }
#pragma unroll
    for (int i = 0; i < 8; ++i) {
        bf16x4 p; p[0]=f2bf(ga[8+i].x); p[1]=f2bf(ga[8+i].y); p[2]=f2bf(ga[8+i].z); p[3]=f2bf(ga[8+i].w);
        *(bf16x4*)(Eb + swz(64 + i * 8 + w, lane * 8)) = p;
    }
    __syncthreads();

    // ---- MFMA: wave w -> tokens w*16..w*16+15, 16 d's ----
    f32x4 accL = {0.f,0.f,0.f,0.f}, accR = accL;
#pragma unroll
    for (int ks = 0; ks < 8; ++ks) {
        bf16x8 a = *(bf16x8*)(Eb + swz(w * 16 + lr, ks * 64 + lk * 16));
        accL = __builtin_amdgcn_mfma_f32_16x16x32_bf16(a, wlf[ks], accL, 0, 0, 0);
        accR = __builtin_amdgcn_mfma_f32_16x16x32_bf16(a, wrf[ks], accR, 0, 0, 0);
    }
    const float blv = bl[dr0 + lr];
    const float brv = br[dr0 + lr];
    // C mapping (m89-verified): col = lane&15 (d), row = (lane>>4)*4 + reg (token)
#pragma unroll
    for (int reg = 0; reg < 4; ++reg) {
        int s = w * 16 + lk * 4 + reg;
        Lcol[lr * 132 + s] = accL[reg] + blv;
        Rcol[lr * 132 + s] = accR[reg] + brv;
    }
    float tl = (accL[0] + accL[1]) + (accL[2] + accL[3]) + blv * 4.0f;
    float tr = (accR[0] + accR[1]) + (accR[2] + accR[3]) + brv * 4.0f;
    tl += __shfl_xor(tl, 16);  tr += __shfl_xor(tr, 16);
    tl += __shfl_xor(tl, 32);  tr += __shfl_xor(tr, 32);
    if (lane < 16) { redwL[w * 16 + lr] = tl; redwR[w * 16 + lr] = tr; }
    __syncthreads();

    // ---- all-pairs |L_i + R_j|: thread (d, jg) does 4 j's x 128 i's ----
    const int d = tid & 15, jg = tid >> 4;
    float rr[4];
    *(float4*)rr = *(float4*)&Rcol[d * 132 + jg * 4];

    float a0 = 0.f, a1 = 0.f, a2 = 0.f, a3 = 0.f;
    for (int i = 0; i < 128; i += 4) {
        float4 l4 = *(float4*)&Lcol[d * 132 + i];
#pragma unroll
        for (int q = 0; q < 4; ++q) {
            a0 += fabsf(l4.x + rr[q]);
            a1 += fabsf(l4.y + rr[q]);
            a2 += fabsf(l4.z + rr[q]);
            a3 += fabsf(l4.w + rr[q]);
        }
    }
    redA[tid] = (a0 + a1) + (a2 + a3);
    __syncthreads();

    if (tid < 16) {
        float sa = 0.f;
#pragma unroll
        for (int g = 0; g < 32; ++g) sa += redA[g * 16 + tid];
        float sl = 0.f, sr = 0.f;
#pragma unroll
        for (int wv = 0; wv < 8; ++wv) {
            sl += redwL[wv * 16 + tid];
            sr += redwR[wv * 16 + tid];
        }
        absS [b * DD + dr0 + tid] = sa;
        sumLg[b * DD + dr0 + tid] = sl;
        sumRg[b * DD + dr0 + tid] = sr;
    }
}

// ---------------- final: pooled affine ----------------
__global__ __launch_bounds__(256) void k_final(
    const float* __restrict__ sumLg, const float* __restrict__ sumRg,
    const float* __restrict__ absS,
    const float* __restrict__ Wrel, const float* __restrict__ brel,
    float* __restrict__ out)
{
    __shared__ float plds[DD];
    const int tid = threadIdx.x;
    const int b   = blockIdx.x;

    float sl = sumLg[b * DD + tid];
    float sr = sumRg[b * DD + tid];
    float sa = absS [b * DD + tid];

    // pooled = (S*(sumL+sumR) + sumAbs) / (2*S*S)
    plds[tid] = (128.0f * (sl + sr) + sa) * (1.0f / 32768.0f);
    __syncthreads();

    float acc = brel[tid];
    const float4* w4 = (const float4*)(Wrel + (size_t)tid * DD);
#pragma unroll
    for (int k4 = 0; k4 < DD / 4; ++k4) {
        float4 p = *(float4*)&plds[k4 * 4];
        float4 w = w4[k4];
        acc = fmaf(p.x, w.x, acc);
        acc = fmaf(p.y, w.y, acc);
        acc = fmaf(p.z, w.z, acc);
        acc = fmaf(p.w, w.w, acc);
    }
    out[b * DD + tid] = acc;
}

extern "C" void kernel_launch(void* const* d_in, const int* in_sizes, int n_in,
                              void* d_out, int out_size, void* d_ws, size_t ws_size,
                              hipStream_t stream) {
    const int*   X    = (const int*)d_in[0];
    const float* emb  = (const float*)d_in[1];
    const float* Wl   = (const float*)d_in[2];
    const float* bl   = (const float*)d_in[3];
    const float* Wr   = (const float*)d_in[4];
    const float* br   = (const float*)d_in[5];
    const float* Wrel = (const float*)d_in[6];
    const float* brel = (const float*)d_in[7];
    float* out = (float*)d_out;

    float* ws    = (float*)d_ws;
    float* sumLg = ws;                 // [B][D]
    float* sumRg = sumLg + BB * DD;    // [B][D]
    float* absS  = sumRg + BB * DD;    // [B][D]

    k_fused<<<BB * 16, 512, 0, stream>>>(X, emb, Wl, bl, Wr, br,
                                         sumLg, sumRg, absS);
    k_final<<<BB, 256, 0, stream>>>(sumLg, sumRg, absS, Wrel, brel, out);
}